// Round 5
// baseline (176.597 us; speedup 1.0000x reference)
//
#include <hip/hip_runtime.h>
#include <math.h>

// Shapes: B=8 S=1024 IN=768 H=8 F=64 ; M=B*S=8192, N=H*F=512, K=768
// Pipeline:
//   conv_w   : W fp32 [768][512] -> WbT bf16 [512][768]          (transpose)
//   gemm_xw  : X fp32 x WbT -> WhT bf16 [bh][f][s]  (MFMA; A via LDS, B-frags
//              loaded DIRECTLY from global - WbT[n][k] is already frag layout)
//   src_dst  : srcT/dstT fp32 [bh][s] = WhT . a_src/a_dst ; mask folded into dstT
//   gat_attn : BARRIER-FREE. P-scores in MFMA A-frags (registers), Wh B-frags
//              loaded directly from global (16B contiguous in WhT[f][s]),
//              PV + l both on the MFMA pipe. No LDS at all.

typedef __attribute__((ext_vector_type(8))) short short8;   // 8 bf16 (4 VGPRs)
typedef __attribute__((ext_vector_type(4))) float floatx4;  // MFMA C/D

union Frag { short8 s8; uint4 u4; };

__device__ inline unsigned as_u(float f) { union { float f; unsigned u; } v; v.f = f; return v.u; }
__device__ inline float as_f(unsigned u) { union { unsigned u; float f; } v; v.u = u; return v.f; }

// RNE pack two fp32 -> bf16x2 (lo = a, hi = b)
__device__ inline unsigned pk_rne(float a, float b) {
  unsigned ua = as_u(a); ua = ua + 0x7fffu + ((ua >> 16) & 1u);
  unsigned ub = as_u(b); ub = ub + 0x7fffu + ((ub >> 16) & 1u);
  return (ua >> 16) | (ub & 0xffff0000u);
}
__device__ inline unsigned short f2bf(float f) {
  unsigned u = as_u(f); u = u + 0x7fffu + ((u >> 16) & 1u);
  return (unsigned short)(u >> 16);
}

// ---------------- conv_w: transpose W (768x512 fp32) -> WbT (512x768 bf16)
__global__ __launch_bounds__(256) void conv_w(const float* __restrict__ W,
                                              unsigned short* __restrict__ WbT) {
  __shared__ unsigned short tile[64][72];  // [n][k], stride 144B (bank-friendly)
  int kt = blockIdx.x >> 3, nt = blockIdx.x & 7;
  int k0 = kt * 64, n0 = nt * 64;
  int t = threadIdx.x;
  int kr = t >> 2, cs = (t & 3) * 16;
#pragma unroll
  for (int q = 0; q < 4; q++) {
    float4 v = *(const float4*)&W[(k0 + kr) * 512 + n0 + cs + q * 4];
    tile[cs + q * 4 + 0][kr] = f2bf(v.x);
    tile[cs + q * 4 + 1][kr] = f2bf(v.y);
    tile[cs + q * 4 + 2][kr] = f2bf(v.z);
    tile[cs + q * 4 + 3][kr] = f2bf(v.w);
  }
  __syncthreads();
  int nr = t >> 2, ks = (t & 3) * 16;
  uint4 d0 = *(const uint4*)&tile[nr][ks];
  uint4 d1 = *(const uint4*)&tile[nr][ks + 8];
  *(uint4*)&WbT[(n0 + nr) * 768 + k0 + ks] = d0;
  *(uint4*)&WbT[(n0 + nr) * 768 + k0 + ks + 8] = d1;
}

// ---------------- gemm_xw: Wh = X @ W, bf16 MFMA, output transposed bf16 WhT[bh*64+f][s]
// tile 128(M) x 64(N), BK=32, grid (8, 64), 256 thr (4 waves, wave tile 64x32).
// A staged via LDS (fp32->bf16 pack); B-frags loaded directly from global
// (WbT[n][k]: frag = 16B contiguous at row n, col k0+quad*8). Both prefetched.
__global__ __launch_bounds__(256) void gemm_xw(const float* __restrict__ X,
                                               const unsigned short* __restrict__ WbT,
                                               unsigned short* __restrict__ WhT) {
  const int LDA = 40;                       // shorts per LDS row (80 B, 16B-aligned)
  __shared__ unsigned short Asm[128 * 40];  // [m][k] bf16
  int t = threadIdx.x, w = t >> 6, lane = t & 63;
  int quad = lane >> 4, l15 = lane & 15;
  int m0 = blockIdx.y * 128, n0 = blockIdx.x * 64;
  int wm = (w & 1) * 64, wn = (w >> 1) * 32;

  floatx4 acc[4][2];
#pragma unroll
  for (int mt = 0; mt < 4; mt++)
#pragma unroll
    for (int nt = 0; nt < 2; nt++)
#pragma unroll
      for (int r = 0; r < 4; r++) acc[mt][nt][r] = 0.f;

  int ar = t >> 1, aks = (t & 1) * 16;  // A staging: row 0..127, float-offset {0,16}
  const float* xbase = &X[(m0 + ar) * 768 + aks];
  const unsigned short* bfp[2];
  bfp[0] = &WbT[(n0 + wn + l15) * 768 + quad * 8];
  bfp[1] = &WbT[(n0 + wn + 16 + l15) * 768 + quad * 8];

  float4 a0 = *(const float4*)&xbase[0];
  float4 a1 = *(const float4*)&xbase[4];
  float4 a2 = *(const float4*)&xbase[8];
  float4 a3 = *(const float4*)&xbase[12];
  Frag fbc[2], fbn[2];
  fbc[0] = *(const Frag*)&bfp[0][0];
  fbc[1] = *(const Frag*)&bfp[1][0];

  for (int kc = 0; kc < 24; kc++) {
    uint4 pa0, pa1;
    pa0.x = pk_rne(a0.x, a0.y); pa0.y = pk_rne(a0.z, a0.w);
    pa0.z = pk_rne(a1.x, a1.y); pa0.w = pk_rne(a1.z, a1.w);
    pa1.x = pk_rne(a2.x, a2.y); pa1.y = pk_rne(a2.z, a2.w);
    pa1.z = pk_rne(a3.x, a3.y); pa1.w = pk_rne(a3.z, a3.w);
    __syncthreads();
    *(uint4*)&Asm[ar * LDA + aks] = pa0;
    *(uint4*)&Asm[ar * LDA + aks + 8] = pa1;
    if (kc < 23) {  // prefetch next k-tile while this one is consumed
      int k0 = (kc + 1) * 32;
      a0 = *(const float4*)&xbase[k0 + 0];
      a1 = *(const float4*)&xbase[k0 + 4];
      a2 = *(const float4*)&xbase[k0 + 8];
      a3 = *(const float4*)&xbase[k0 + 12];
      fbn[0] = *(const Frag*)&bfp[0][k0];
      fbn[1] = *(const Frag*)&bfp[1][k0];
    }
    __syncthreads();
#pragma unroll
    for (int mt = 0; mt < 4; mt++) {
      Frag fa = *(const Frag*)&Asm[(wm + mt * 16 + l15) * LDA + quad * 8];
#pragma unroll
      for (int nt = 0; nt < 2; nt++)
        acc[mt][nt] = __builtin_amdgcn_mfma_f32_16x16x32_bf16(fa.s8, fbc[nt].s8, acc[mt][nt], 0, 0, 0);
    }
    fbc[0] = fbn[0];
    fbc[1] = fbn[1];
  }
  // epilogue: D row = quad*4+r (m), col = l15 (n); store 4 consecutive s as bf16x4 (8B)
#pragma unroll
  for (int mt = 0; mt < 4; mt++) {
#pragma unroll
    for (int nt = 0; nt < 2; nt++) {
      int n = n0 + wn + nt * 16 + l15;
      int h = n >> 6, f = n & 63;
      int m = m0 + wm + mt * 16 + quad * 4;
      int b = m >> 10, s = m & 1023;
      floatx4 c = acc[mt][nt];
      uint2 st;
      st.x = pk_rne(c[0], c[1]);
      st.y = pk_rne(c[2], c[3]);
      *(uint2*)&WhT[((b * 8 + h) * 64 + f) * 1024 + s] = st;
    }
  }
}

// ---------------- src_dst: srcT/dstT[bh][s] = sum_f WhT[bh][f][s] * a_{src,dst}[f]
// Mask folded into dstT: masked j -> -1e30 -> exp gives exactly 0 in gat_attn.
__global__ __launch_bounds__(256) void src_dst(const unsigned short* __restrict__ WhT,
                                               const float* __restrict__ a,
                                               const int* __restrict__ mask,
                                               float* __restrict__ srcT,
                                               float* __restrict__ dstT) {
  int bh = blockIdx.x >> 1;
  int s2 = (blockIdx.x & 1) * 512 + threadIdx.x * 2;
  const unsigned short* base = &WhT[bh * 64 * 1024 + s2];
  float s0 = 0.f, s1 = 0.f, d0 = 0.f, d1 = 0.f;
#pragma unroll 8
  for (int f = 0; f < 64; f++) {
    unsigned uu = *(const unsigned*)&base[f * 1024];
    float x0 = as_f(uu << 16);
    float x1 = as_f(uu & 0xffff0000u);
    float af = a[f], ad = a[64 + f];
    s0 = fmaf(x0, af, s0); s1 = fmaf(x1, af, s1);
    d0 = fmaf(x0, ad, d0); d1 = fmaf(x1, ad, d1);
  }
  int b = bh >> 3;
  int2 mk = *(const int2*)&mask[b * 1024 + s2];
  float2 sv = {s0, s1};
  float2 dv = {mk.x ? d0 : -1e30f, mk.y ? d1 : -1e30f};
  *(float2*)&srcT[bh * 1024 + s2] = sv;
  *(float2*)&dstT[bh * 1024 + s2] = dv;
}

// ---------------- gat_attn: BARRIER-FREE, NO LDS.
// grid (16, 64) = (i-tiles of 64, bh), 256 thr = 4 waves; wave w owns 16 rows
// (iw = i0 + w*16) -> 4096 waves total = 16 waves/CU (50% occupancy cap).
// Per j-tile (64 j): 8 B-frags direct from global (WhT[f][j]: each frag is a
// contiguous 16B run; per wave-instr the 4 quads x 16 rows cover full 64B
// lines -> perfectly coalesced, L1/L2-served, shared by 4 waves x 16 i-blocks).
// Scores (|e|<~1, exp can't overflow; mask pre-folded into dstT as -1e30)
// built straight into the MFMA A-fragment; l accumulated on the MFMA pipe
// with a ones-B (sums exactly the bf16-truncated p -> same C-rows as acc).
__global__ __launch_bounds__(256) void gat_attn(const unsigned short* __restrict__ WhT,
                                                const float* __restrict__ srcT,
                                                const float* __restrict__ dstT,
                                                float* __restrict__ out) {
  int t = threadIdx.x, w = t >> 6, lane = t & 63;
  int quad = lane >> 4, l15 = lane & 15;
  int bh = blockIdx.y, b = bh >> 3;
  int iw = blockIdx.x * 64 + w * 16;

  floatx4 acc[4], lacc;
#pragma unroll
  for (int ft = 0; ft < 4; ft++)
#pragma unroll
    for (int r = 0; r < 4; r++) acc[ft][r] = 0.f;
#pragma unroll
  for (int r = 0; r < 4; r++) lacc[r] = 0.f;

  float src_r = srcT[bh * 1024 + iw + l15];

  Frag ones;
  ones.u4.x = 0x3F803F80u; ones.u4.y = 0x3F803F80u;
  ones.u4.z = 0x3F803F80u; ones.u4.w = 0x3F803F80u;

  const unsigned short* Wg = WhT + bh * 64 * 1024 + l15 * 1024 + quad * 8;
  const float* dbase = &dstT[bh * 1024 + quad * 8];

  for (int j0 = 0; j0 < 1024; j0 += 64) {
    // 1) B-fragments straight from global (8 x 16B per lane)
    Frag fb[2][4];
#pragma unroll
    for (int jc = 0; jc < 2; jc++)
#pragma unroll
      for (int ft = 0; ft < 4; ft++)
        fb[jc][ft] = *(const Frag*)&Wg[ft * 16 * 1024 + j0 + jc * 32];
    // 2) scores -> A-fragments (VALU; overlaps the frag-load latency)
    Frag fragA[2];
#pragma unroll
    for (int jc = 0; jc < 2; jc++) {
      float4 dv0 = *(const float4*)&dbase[j0 + jc * 32];
      float4 dv1 = *(const float4*)&dbase[j0 + jc * 32 + 4];
      float dj[8] = {dv0.x, dv0.y, dv0.z, dv0.w, dv1.x, dv1.y, dv1.z, dv1.w};
      unsigned pw[4];
#pragma unroll
      for (int pr = 0; pr < 4; pr++) {
        float x0 = src_r + dj[pr * 2];
        float x1 = src_r + dj[pr * 2 + 1];
        x0 = fmaxf(x0, 0.2f * x0);  // leaky_relu (alpha<1)
        x1 = fmaxf(x1, 0.2f * x1);
        float p0 = __expf(x0), p1 = __expf(x1);
        pw[pr] = (as_u(p0) >> 16) | (as_u(p1) & 0xffff0000u);  // truncate to bf16x2
      }
      fragA[jc].u4.x = pw[0];
      fragA[jc].u4.y = pw[1];
      fragA[jc].u4.z = pw[2];
      fragA[jc].u4.w = pw[3];
    }
    // 3) MFMA: acc[ft] += P(16x32) x Wh(32x16) ; lacc += P x ones
#pragma unroll
    for (int jc = 0; jc < 2; jc++) {
#pragma unroll
      for (int ft = 0; ft < 4; ft++)
        acc[ft] = __builtin_amdgcn_mfma_f32_16x16x32_bf16(fragA[jc].s8, fb[jc][ft].s8,
                                                          acc[ft], 0, 0, 0);
      lacc = __builtin_amdgcn_mfma_f32_16x16x32_bf16(fragA[jc].s8, ones.s8, lacc, 0, 0, 0);
    }
  }
  // epilogue: C row = quad*4+r, col = l15; lacc rows align with acc rows
  float inv[4] = {1.f / lacc[0], 1.f / lacc[1], 1.f / lacc[2], 1.f / lacc[3]};
  int mrow = b * 1024 + iw + quad * 4;
#pragma unroll
  for (int ft = 0; ft < 4; ft++) {
    int col = (bh & 7) * 64 + ft * 16 + l15;
#pragma unroll
    for (int r = 0; r < 4; r++)
      out[(mrow + r) * 512 + col] = acc[ft][r] * inv[r];
  }
}

extern "C" void kernel_launch(void* const* d_in, const int* in_sizes, int n_in,
                              void* d_out, int out_size, void* d_ws, size_t ws_size,
                              hipStream_t stream) {
  const float* X = (const float*)d_in[0];   // (8,1024,768)
  const int* mask = (const int*)d_in[1];    // (8,1024)
  const float* W = (const float*)d_in[2];   // (768,512)
  const float* a = (const float*)d_in[3];   // (128,)
  float* out = (float*)d_out;               // (8,1024,512)

  char* ws = (char*)d_ws;
  unsigned short* WhT = (unsigned short*)ws;                    // 64*64*1024 bf16 = 8388608 B
  unsigned short* WbT = (unsigned short*)(ws + 8388608);        // 512*768 bf16  = 786432 B
  float* srcT = (float*)(ws + 9175040);                         // 64*1024 f32   = 262144 B
  float* dstT = (float*)(ws + 9437184);                         // 64*1024 f32

  conv_w<<<96, 256, 0, stream>>>(W, WbT);
  gemm_xw<<<dim3(8, 64), 256, 0, stream>>>(X, WbT, WhT);
  src_dst<<<128, 256, 0, stream>>>(WhT, a, mask, srcT, dstT);
  gat_attn<<<dim3(16, 64), 256, 0, stream>>>(WhT, srcT, dstT, out);
}

// Round 6
// 137.483 us; speedup vs baseline: 1.2845x; 1.2845x over previous
//
#include <hip/hip_runtime.h>
#include <math.h>

// Shapes: B=8 S=1024 IN=768 H=8 F=64 ; M=B*S=8192, N=H*F=512, K=768
// Pipeline:
//   conv_w   : W fp32 [768][512] -> WbT bf16 [512][768]          (transpose)
//   gemm_xw  : X fp32 x WbT -> WhT bf16 [bh][f][s]  (MFMA; A via LDS+prefetch,
//              B-frags direct from global - WbT[n][k] is already frag layout;
//              64x64 tiles, grid(8,128)=1024 blocks -> 16 waves/CU)
//   src_dst  : srcT/dstT fp32 [bh][s] = WhT . a_src/a_dst ; mask folded into dstT
//   gat_attn : P-scores in MFMA A-frags (registers), Wh j-tile staged in LDS
//              (prefetched), PV + l on the MFMA pipe; grid(16,64)=1024 blocks,
//              256 thr -> 16 waves/CU. Latency decoupled via LDS, unlike R4's
//              global-direct version (which exposed raw L2 latency to MFMA).

typedef __attribute__((ext_vector_type(8))) short short8;   // 8 bf16 (4 VGPRs)
typedef __attribute__((ext_vector_type(4))) float floatx4;  // MFMA C/D

union Frag { short8 s8; uint4 u4; };

__device__ inline unsigned as_u(float f) { union { float f; unsigned u; } v; v.f = f; return v.u; }
__device__ inline float as_f(unsigned u) { union { unsigned u; float f; } v; v.u = u; return v.f; }

// RNE pack two fp32 -> bf16x2 (lo = a, hi = b)
__device__ inline unsigned pk_rne(float a, float b) {
  unsigned ua = as_u(a); ua = ua + 0x7fffu + ((ua >> 16) & 1u);
  unsigned ub = as_u(b); ub = ub + 0x7fffu + ((ub >> 16) & 1u);
  return (ua >> 16) | (ub & 0xffff0000u);
}
__device__ inline unsigned short f2bf(float f) {
  unsigned u = as_u(f); u = u + 0x7fffu + ((u >> 16) & 1u);
  return (unsigned short)(u >> 16);
}

// ---------------- conv_w: transpose W (768x512 fp32) -> WbT (512x768 bf16)
__global__ __launch_bounds__(256) void conv_w(const float* __restrict__ W,
                                              unsigned short* __restrict__ WbT) {
  __shared__ unsigned short tile[64][72];  // [n][k], stride 144B (bank-friendly)
  int kt = blockIdx.x >> 3, nt = blockIdx.x & 7;
  int k0 = kt * 64, n0 = nt * 64;
  int t = threadIdx.x;
  int kr = t >> 2, cs = (t & 3) * 16;
#pragma unroll
  for (int q = 0; q < 4; q++) {
    float4 v = *(const float4*)&W[(k0 + kr) * 512 + n0 + cs + q * 4];
    tile[cs + q * 4 + 0][kr] = f2bf(v.x);
    tile[cs + q * 4 + 1][kr] = f2bf(v.y);
    tile[cs + q * 4 + 2][kr] = f2bf(v.z);
    tile[cs + q * 4 + 3][kr] = f2bf(v.w);
  }
  __syncthreads();
  int nr = t >> 2, ks = (t & 3) * 16;
  uint4 d0 = *(const uint4*)&tile[nr][ks];
  uint4 d1 = *(const uint4*)&tile[nr][ks + 8];
  *(uint4*)&WbT[(n0 + nr) * 768 + k0 + ks] = d0;
  *(uint4*)&WbT[(n0 + nr) * 768 + k0 + ks + 8] = d1;
}

// ---------------- gemm_xw: Wh = X @ W, bf16 MFMA, output transposed bf16 WhT[bh*64+f][s]
// tile 64(M) x 64(N), BK=32, grid (8, 128) = 1024 blocks, 256 thr = 4 waves.
// Wave tile 32x32 (2x2 m/n 16-tiles). A staged via LDS (fp32->bf16 pack,
// 80B-padded rows); B-frags direct from global (WbT row n, 16B contiguous,
// L2-resident 768KB). Next k-tile's A+B loads issued before the compute phase.
__global__ __launch_bounds__(256) void gemm_xw(const float* __restrict__ X,
                                               const unsigned short* __restrict__ WbT,
                                               unsigned short* __restrict__ WhT) {
  const int LDA = 40;                      // shorts per LDS row (80 B, 16B-aligned)
  __shared__ unsigned short Asm[64 * 40];  // [m][k] bf16, 5 KB
  int t = threadIdx.x, w = t >> 6, lane = t & 63;
  int quad = lane >> 4, l15 = lane & 15;
  int m0 = blockIdx.y * 64, n0 = blockIdx.x * 64;
  int wm = (w & 1) * 32, wn = (w >> 1) * 32;

  floatx4 acc[2][2];
#pragma unroll
  for (int mt = 0; mt < 2; mt++)
#pragma unroll
    for (int nt = 0; nt < 2; nt++)
#pragma unroll
      for (int r = 0; r < 4; r++) acc[mt][nt][r] = 0.f;

  int at = t >> 2, ak = (t & 3) * 8;  // A staging: row 0..63, float-offset {0,8,16,24}
  const float* xbase = &X[(m0 + at) * 768 + ak];
  const unsigned short* bfp0 = &WbT[(n0 + wn + l15) * 768 + quad * 8];
  const unsigned short* bfp1 = &WbT[(n0 + wn + 16 + l15) * 768 + quad * 8];

  float4 a0 = *(const float4*)&xbase[0];
  float4 a1 = *(const float4*)&xbase[4];
  Frag fb0c = *(const Frag*)&bfp0[0];
  Frag fb1c = *(const Frag*)&bfp1[0];

  for (int kc = 0; kc < 24; kc++) {
    uint4 pa;
    pa.x = pk_rne(a0.x, a0.y); pa.y = pk_rne(a0.z, a0.w);
    pa.z = pk_rne(a1.x, a1.y); pa.w = pk_rne(a1.z, a1.w);
    __syncthreads();
    *(uint4*)&Asm[at * LDA + ak] = pa;
    Frag fb0n = fb0c, fb1n = fb1c;
    if (kc < 23) {  // prefetch next k-tile while this one is consumed
      int k0 = (kc + 1) * 32;
      a0 = *(const float4*)&xbase[k0 + 0];
      a1 = *(const float4*)&xbase[k0 + 4];
      fb0n = *(const Frag*)&bfp0[k0];
      fb1n = *(const Frag*)&bfp1[k0];
    }
    __syncthreads();
    Frag fa0 = *(const Frag*)&Asm[(wm + l15) * LDA + quad * 8];
    Frag fa1 = *(const Frag*)&Asm[(wm + 16 + l15) * LDA + quad * 8];
    acc[0][0] = __builtin_amdgcn_mfma_f32_16x16x32_bf16(fa0.s8, fb0c.s8, acc[0][0], 0, 0, 0);
    acc[0][1] = __builtin_amdgcn_mfma_f32_16x16x32_bf16(fa0.s8, fb1c.s8, acc[0][1], 0, 0, 0);
    acc[1][0] = __builtin_amdgcn_mfma_f32_16x16x32_bf16(fa1.s8, fb0c.s8, acc[1][0], 0, 0, 0);
    acc[1][1] = __builtin_amdgcn_mfma_f32_16x16x32_bf16(fa1.s8, fb1c.s8, acc[1][1], 0, 0, 0);
    fb0c = fb0n;
    fb1c = fb1n;
  }
  // epilogue: D row = quad*4+r (m), col = l15 (n); store 4 consecutive s as bf16x4 (8B)
  int h = n0 >> 6;  // n-tile is 64-aligned: whole block is one head
#pragma unroll
  for (int mt = 0; mt < 2; mt++) {
#pragma unroll
    for (int nt = 0; nt < 2; nt++) {
      int f = (wn + nt * 16 + l15) & 63;
      int m = m0 + wm + mt * 16 + quad * 4;
      int b = m >> 10, s = m & 1023;
      floatx4 c = acc[mt][nt];
      uint2 st;
      st.x = pk_rne(c[0], c[1]);
      st.y = pk_rne(c[2], c[3]);
      *(uint2*)&WhT[((b * 8 + h) * 64 + f) * 1024 + s] = st;
    }
  }
}

// ---------------- src_dst: srcT/dstT[bh][s] = sum_f WhT[bh][f][s] * a_{src,dst}[f]
// Mask folded into dstT: masked j -> -1e30 -> exp gives exactly 0 in gat_attn.
__global__ __launch_bounds__(256) void src_dst(const unsigned short* __restrict__ WhT,
                                               const float* __restrict__ a,
                                               const int* __restrict__ mask,
                                               float* __restrict__ srcT,
                                               float* __restrict__ dstT) {
  int bh = blockIdx.x >> 1;
  int s2 = (blockIdx.x & 1) * 512 + threadIdx.x * 2;
  const unsigned short* base = &WhT[bh * 64 * 1024 + s2];
  float s0 = 0.f, s1 = 0.f, d0 = 0.f, d1 = 0.f;
#pragma unroll 8
  for (int f = 0; f < 64; f++) {
    unsigned uu = *(const unsigned*)&base[f * 1024];
    float x0 = as_f(uu << 16);
    float x1 = as_f(uu & 0xffff0000u);
    float af = a[f], ad = a[64 + f];
    s0 = fmaf(x0, af, s0); s1 = fmaf(x1, af, s1);
    d0 = fmaf(x0, ad, d0); d1 = fmaf(x1, ad, d1);
  }
  int b = bh >> 3;
  int2 mk = *(const int2*)&mask[b * 1024 + s2];
  float2 sv = {s0, s1};
  float2 dv = {mk.x ? d0 : -1e30f, mk.y ? d1 : -1e30f};
  *(float2*)&srcT[bh * 1024 + s2] = sv;
  *(float2*)&dstT[bh * 1024 + s2] = dv;
}

// ---------------- gat_attn: LDS-staged, prefetched, high-occupancy.
// grid (16, 64) = (i-tiles of 64, bh), 256 thr = 4 waves; wave w owns rows
// iw = i0 + w*16 -> 1024 blocks, 4 blocks/CU, 16 waves/CU (50% cap).
// Per j-tile: stage Wh (64f x 64j bf16 = 8KB) into LDS (XOR-swizzled 16B
// blocks; next tile's global loads issued before the compute barrier),
// scores -> A-frags in registers (|e|<~1 so exp can't overflow; mask
// pre-folded into dstT), PV + l (ones-B) on the MFMA pipe.
__global__ __launch_bounds__(256) void gat_attn(const unsigned short* __restrict__ WhT,
                                                const float* __restrict__ srcT,
                                                const float* __restrict__ dstT,
                                                float* __restrict__ out) {
  __shared__ unsigned short Bs[64 * 64];  // [f][j] bf16, swizzle: pb = kb ^ (f&7)
  int t = threadIdx.x, w = t >> 6, lane = t & 63;
  int quad = lane >> 4, l15 = lane & 15;
  int bh = blockIdx.y, b = bh >> 3;
  int iw = blockIdx.x * 64 + w * 16;

  floatx4 acc[4], lacc;
#pragma unroll
  for (int ft = 0; ft < 4; ft++)
#pragma unroll
    for (int r = 0; r < 4; r++) acc[ft][r] = 0.f;
#pragma unroll
  for (int r = 0; r < 4; r++) lacc[r] = 0.f;

  float src_r = srcT[bh * 1024 + iw + l15];

  Frag ones;
  ones.u4.x = 0x3F803F80u; ones.u4.y = 0x3F803F80u;
  ones.u4.z = 0x3F803F80u; ones.u4.w = 0x3F803F80u;

  const unsigned short* Wg = WhT + bh * 64 * 1024;
  const float* dbase = &dstT[bh * 1024 + quad * 8];
  int sf0 = t >> 3, skb = t & 7;  // staging: f rows {sf0, sf0+32}, 16B block idx
  int swz = (skb ^ (sf0 & 7)) * 8;  // (sf0+32)&7 == sf0&7

  // prefetch first tile
  uint4 g0 = *(const uint4*)&Wg[sf0 * 1024 + skb * 8];
  uint4 g1 = *(const uint4*)&Wg[(sf0 + 32) * 1024 + skb * 8];

  for (int j0 = 0; j0 < 1024; j0 += 64) {
    __syncthreads();  // prior iter's LDS reads done
    *(uint4*)&Bs[sf0 * 64 + swz] = g0;
    *(uint4*)&Bs[(sf0 + 32) * 64 + swz] = g1;
    if (j0 < 960) {  // prefetch next tile; in flight through the MFMA phase
      g0 = *(const uint4*)&Wg[sf0 * 1024 + j0 + 64 + skb * 8];
      g1 = *(const uint4*)&Wg[(sf0 + 32) * 1024 + j0 + 64 + skb * 8];
    }
    // scores -> A-fragments (VALU, no LDS dependence)
    Frag fragA[2];
#pragma unroll
    for (int jc = 0; jc < 2; jc++) {
      float4 dv0 = *(const float4*)&dbase[j0 + jc * 32];
      float4 dv1 = *(const float4*)&dbase[j0 + jc * 32 + 4];
      float dj[8] = {dv0.x, dv0.y, dv0.z, dv0.w, dv1.x, dv1.y, dv1.z, dv1.w};
      unsigned pw[4];
#pragma unroll
      for (int pr = 0; pr < 4; pr++) {
        float x0 = src_r + dj[pr * 2];
        float x1 = src_r + dj[pr * 2 + 1];
        x0 = fmaxf(x0, 0.2f * x0);  // leaky_relu (alpha<1)
        x1 = fmaxf(x1, 0.2f * x1);
        float p0 = __expf(x0), p1 = __expf(x1);
        pw[pr] = (as_u(p0) >> 16) | (as_u(p1) & 0xffff0000u);  // truncate to bf16x2
      }
      fragA[jc].u4.x = pw[0];
      fragA[jc].u4.y = pw[1];
      fragA[jc].u4.z = pw[2];
      fragA[jc].u4.w = pw[3];
    }
    __syncthreads();  // staging visible
    // MFMA: acc[ft] += P(16x32) x Wh(32x16) ; lacc += P x ones
#pragma unroll
    for (int jc = 0; jc < 2; jc++) {
      Frag fbr[4];
#pragma unroll
      for (int ft = 0; ft < 4; ft++) {
        int f = ft * 16 + l15;
        int kb = jc * 4 + quad;
        fbr[ft] = *(const Frag*)&Bs[f * 64 + (kb ^ (f & 7)) * 8];
      }
#pragma unroll
      for (int ft = 0; ft < 4; ft++)
        acc[ft] = __builtin_amdgcn_mfma_f32_16x16x32_bf16(fragA[jc].s8, fbr[ft].s8,
                                                          acc[ft], 0, 0, 0);
      lacc = __builtin_amdgcn_mfma_f32_16x16x32_bf16(fragA[jc].s8, ones.s8, lacc, 0, 0, 0);
    }
  }
  // epilogue: C row = quad*4+r, col = l15; lacc rows align with acc rows
  float inv[4] = {1.f / lacc[0], 1.f / lacc[1], 1.f / lacc[2], 1.f / lacc[3]};
  int mrow = b * 1024 + iw + quad * 4;
#pragma unroll
  for (int ft = 0; ft < 4; ft++) {
    int col = (bh & 7) * 64 + ft * 16 + l15;
#pragma unroll
    for (int r = 0; r < 4; r++)
      out[(mrow + r) * 512 + col] = acc[ft][r] * inv[r];
  }
}

extern "C" void kernel_launch(void* const* d_in, const int* in_sizes, int n_in,
                              void* d_out, int out_size, void* d_ws, size_t ws_size,
                              hipStream_t stream) {
  const float* X = (const float*)d_in[0];   // (8,1024,768)
  const int* mask = (const int*)d_in[1];    // (8,1024)
  const float* W = (const float*)d_in[2];   // (768,512)
  const float* a = (const float*)d_in[3];   // (128,)
  float* out = (float*)d_out;               // (8,1024,512)

  char* ws = (char*)d_ws;
  unsigned short* WhT = (unsigned short*)ws;                    // 64*64*1024 bf16 = 8388608 B
  unsigned short* WbT = (unsigned short*)(ws + 8388608);        // 512*768 bf16  = 786432 B
  float* srcT = (float*)(ws + 9175040);                         // 64*1024 f32   = 262144 B
  float* dstT = (float*)(ws + 9437184);                         // 64*1024 f32

  conv_w<<<96, 256, 0, stream>>>(W, WbT);
  gemm_xw<<<dim3(8, 128), 256, 0, stream>>>(X, WbT, WhT);
  src_dst<<<128, 256, 0, stream>>>(WhT, a, mask, srcT, dstT);
  gat_attn<<<dim3(16, 64), 256, 0, stream>>>(WhT, srcT, dstT, out);
}

// Round 7
// 129.448 us; speedup vs baseline: 1.3642x; 1.0621x over previous
//
#include <hip/hip_runtime.h>
#include <math.h>

// Shapes: B=8 S=1024 IN=768 H=8 F=64 ; M=B*S=8192, N=H*F=512, K=768
// Pipeline (3 kernels):
//   conv_w   : W fp32 [768][512] -> WbT bf16 [512][768]          (transpose)
//   gemm_xw  : X fp32 x WbT -> WhT bf16 [bh][f][s]  (MFMA) + FUSED src/dst
//              epilogue (each block = 64 s-rows x one full head -> per-(s,h)
//              src/dst from fp32 acc; mask folded into dstT).
//              Grid (x=m:128, y=n:8): linear id = m+128n -> XCD = m%8, so all
//              8 n-blocks sharing an X m-tile sit on ONE XCD -> X read from
//              HBM once (25 MB) instead of 8x (201 MB).
//   gat_attn : P-scores in MFMA A-frags, Wh j-tile staged in LDS (prefetched),
//              PV + l on the MFMA pipe. Grid (x=bh:64, y=i:16) -> XCD = bh%8:
//              all 16 i-blocks of a bh share one XCD's L2 for the Wh slice.

typedef __attribute__((ext_vector_type(8))) short short8;   // 8 bf16 (4 VGPRs)
typedef __attribute__((ext_vector_type(4))) float floatx4;  // MFMA C/D

union Frag { short8 s8; uint4 u4; };

__device__ inline unsigned as_u(float f) { union { float f; unsigned u; } v; v.f = f; return v.u; }
__device__ inline float as_f(unsigned u) { union { unsigned u; float f; } v; v.u = u; return v.f; }

// RNE pack two fp32 -> bf16x2 (lo = a, hi = b)
__device__ inline unsigned pk_rne(float a, float b) {
  unsigned ua = as_u(a); ua = ua + 0x7fffu + ((ua >> 16) & 1u);
  unsigned ub = as_u(b); ub = ub + 0x7fffu + ((ub >> 16) & 1u);
  return (ua >> 16) | (ub & 0xffff0000u);
}
__device__ inline unsigned short f2bf(float f) {
  unsigned u = as_u(f); u = u + 0x7fffu + ((u >> 16) & 1u);
  return (unsigned short)(u >> 16);
}

// ---------------- conv_w: transpose W (768x512 fp32) -> WbT (512x768 bf16)
__global__ __launch_bounds__(256) void conv_w(const float* __restrict__ W,
                                              unsigned short* __restrict__ WbT) {
  __shared__ unsigned short tile[64][72];  // [n][k], stride 144B (bank-friendly)
  int kt = blockIdx.x >> 3, nt = blockIdx.x & 7;
  int k0 = kt * 64, n0 = nt * 64;
  int t = threadIdx.x;
  int kr = t >> 2, cs = (t & 3) * 16;
#pragma unroll
  for (int q = 0; q < 4; q++) {
    float4 v = *(const float4*)&W[(k0 + kr) * 512 + n0 + cs + q * 4];
    tile[cs + q * 4 + 0][kr] = f2bf(v.x);
    tile[cs + q * 4 + 1][kr] = f2bf(v.y);
    tile[cs + q * 4 + 2][kr] = f2bf(v.z);
    tile[cs + q * 4 + 3][kr] = f2bf(v.w);
  }
  __syncthreads();
  int nr = t >> 2, ks = (t & 3) * 16;
  uint4 d0 = *(const uint4*)&tile[nr][ks];
  uint4 d1 = *(const uint4*)&tile[nr][ks + 8];
  *(uint4*)&WbT[(n0 + nr) * 768 + k0 + ks] = d0;
  *(uint4*)&WbT[(n0 + nr) * 768 + k0 + ks + 8] = d1;
}

// ---------------- gemm_xw: Wh = X @ W (bf16 MFMA) + fused src/dst epilogue.
// tile 64(M) x 64(N), BK=32, grid (128 m, 8 n) = 1024 blocks, 256 thr = 4 waves.
// Wave tile 32x32. A staged via LDS (fp32->bf16 pack, 80B rows); B-frags direct
// from global (WbT row n, 16B contiguous, L2-resident). Prefetch 1 k-tile deep.
__global__ __launch_bounds__(256) void gemm_xw(const float* __restrict__ X,
                                               const unsigned short* __restrict__ WbT,
                                               const float* __restrict__ a,
                                               const int* __restrict__ mask,
                                               unsigned short* __restrict__ WhT,
                                               float* __restrict__ srcT,
                                               float* __restrict__ dstT) {
  const int LDA = 40;                      // shorts per LDS row (80 B, 16B-aligned)
  __shared__ unsigned short Asm[64 * 40];  // [m][k] bf16, 5 KB
  __shared__ float sd[2][64], dd[2][64];   // fused src/dst cross-wave partials
  int t = threadIdx.x, w = t >> 6, lane = t & 63;
  int quad = lane >> 4, l15 = lane & 15;
  int m0 = blockIdx.x * 64, n0 = blockIdx.y * 64;
  int wm = (w & 1) * 32, wn = (w >> 1) * 32;

  floatx4 acc[2][2];
#pragma unroll
  for (int mt = 0; mt < 2; mt++)
#pragma unroll
    for (int nt = 0; nt < 2; nt++)
#pragma unroll
      for (int r = 0; r < 4; r++) acc[mt][nt][r] = 0.f;

  int at = t >> 2, ak = (t & 3) * 8;  // A staging: row 0..63, float-offset {0,8,16,24}
  const float* xbase = &X[(m0 + at) * 768 + ak];
  const unsigned short* bfp0 = &WbT[(n0 + wn + l15) * 768 + quad * 8];
  const unsigned short* bfp1 = &WbT[(n0 + wn + 16 + l15) * 768 + quad * 8];

  float4 a0 = *(const float4*)&xbase[0];
  float4 a1 = *(const float4*)&xbase[4];
  Frag fb0c = *(const Frag*)&bfp0[0];
  Frag fb1c = *(const Frag*)&bfp1[0];

  for (int kc = 0; kc < 24; kc++) {
    uint4 pa;
    pa.x = pk_rne(a0.x, a0.y); pa.y = pk_rne(a0.z, a0.w);
    pa.z = pk_rne(a1.x, a1.y); pa.w = pk_rne(a1.z, a1.w);
    __syncthreads();
    *(uint4*)&Asm[at * LDA + ak] = pa;
    Frag fb0n = fb0c, fb1n = fb1c;
    if (kc < 23) {  // prefetch next k-tile while this one is consumed
      int k0 = (kc + 1) * 32;
      a0 = *(const float4*)&xbase[k0 + 0];
      a1 = *(const float4*)&xbase[k0 + 4];
      fb0n = *(const Frag*)&bfp0[k0];
      fb1n = *(const Frag*)&bfp1[k0];
    }
    __syncthreads();
    Frag fa0 = *(const Frag*)&Asm[(wm + l15) * LDA + quad * 8];
    Frag fa1 = *(const Frag*)&Asm[(wm + 16 + l15) * LDA + quad * 8];
    acc[0][0] = __builtin_amdgcn_mfma_f32_16x16x32_bf16(fa0.s8, fb0c.s8, acc[0][0], 0, 0, 0);
    acc[0][1] = __builtin_amdgcn_mfma_f32_16x16x32_bf16(fa0.s8, fb1c.s8, acc[0][1], 0, 0, 0);
    acc[1][0] = __builtin_amdgcn_mfma_f32_16x16x32_bf16(fa1.s8, fb0c.s8, acc[1][0], 0, 0, 0);
    acc[1][1] = __builtin_amdgcn_mfma_f32_16x16x32_bf16(fa1.s8, fb1c.s8, acc[1][1], 0, 0, 0);
    fb0c = fb0n;
    fb1c = fb1n;
  }
  int h = n0 >> 6;  // n-tile is 64-aligned: whole block is one head
  // ---- store WhT: D row = quad*4+r (m), col = l15 (f); 4 consecutive s as bf16x4
#pragma unroll
  for (int mt = 0; mt < 2; mt++) {
#pragma unroll
    for (int nt = 0; nt < 2; nt++) {
      int f = (wn + nt * 16 + l15) & 63;
      int m = m0 + wm + mt * 16 + quad * 4;
      int b = m >> 10, s = m & 1023;
      floatx4 c = acc[mt][nt];
      uint2 st;
      st.x = pk_rne(c[0], c[1]);
      st.y = pk_rne(c[2], c[3]);
      *(uint2*)&WhT[((b * 8 + h) * 64 + f) * 1024 + s] = st;
    }
  }
  // ---- fused src/dst: src[s]=sum_f Wh[s][f]*a[f], dst likewise with a[64+f];
  // thread's f = wn+nt*16+l15; reduce over l15 lanes, then the 2 wn-halves via LDS.
  {
    float asv[2] = {a[wn + l15], a[wn + 16 + l15]};
    float adv[2] = {a[64 + wn + l15], a[64 + wn + 16 + l15]};
    float psrc[2][4], pdst[2][4];
#pragma unroll
    for (int mt = 0; mt < 2; mt++)
#pragma unroll
      for (int r = 0; r < 4; r++) {
        psrc[mt][r] = acc[mt][0][r] * asv[0] + acc[mt][1][r] * asv[1];
        pdst[mt][r] = acc[mt][0][r] * adv[0] + acc[mt][1][r] * adv[1];
      }
#pragma unroll
    for (int off = 1; off < 16; off <<= 1)
#pragma unroll
      for (int mt = 0; mt < 2; mt++)
#pragma unroll
        for (int r = 0; r < 4; r++) {
          psrc[mt][r] += __shfl_xor(psrc[mt][r], off);
          pdst[mt][r] += __shfl_xor(pdst[mt][r], off);
        }
    if (l15 == 0) {
      int half = w >> 1;  // which f-half this wave owns
#pragma unroll
      for (int mt = 0; mt < 2; mt++)
#pragma unroll
        for (int r = 0; r < 4; r++) {
          int m = wm + mt * 16 + quad * 4 + r;
          sd[half][m] = psrc[mt][r];
          dd[half][m] = pdst[mt][r];
        }
    }
    __syncthreads();
    if (t < 64) {
      int m = m0 + t;
      int b = m >> 10, s = m & 1023;
      float sv = sd[0][t] + sd[1][t];
      float dv = dd[0][t] + dd[1][t];
      srcT[(b * 8 + h) * 1024 + s] = sv;
      dstT[(b * 8 + h) * 1024 + s] = mask[b * 1024 + s] ? dv : -1e30f;
    }
  }
}

// ---------------- gat_attn: LDS-staged, prefetched, XCD-local.
// grid (64 bh, 16 i-tiles) -> linear id = bh + 64*i, XCD = bh%8: all 16
// i-blocks of one bh share an XCD -> Wh slice served from that XCD's L2.
// 256 thr = 4 waves; wave w owns rows iw = i0 + w*16 -> 16 waves/CU.
// Per j-tile: stage Wh (64f x 64j bf16 = 8KB) into LDS (XOR-swizzled 16B
// blocks; next tile prefetched into registers before the compute barrier),
// scores -> A-frags (|e|<~1 so exp can't overflow; mask pre-folded into
// dstT as -1e30), PV + l (ones-B) on the MFMA pipe.
__global__ __launch_bounds__(256) void gat_attn(const unsigned short* __restrict__ WhT,
                                                const float* __restrict__ srcT,
                                                const float* __restrict__ dstT,
                                                float* __restrict__ out) {
  __shared__ unsigned short Bs[64 * 64];  // [f][j] bf16, swizzle: pb = kb ^ (f&7)
  int t = threadIdx.x, w = t >> 6, lane = t & 63;
  int quad = lane >> 4, l15 = lane & 15;
  int bh = blockIdx.x, b = bh >> 3;
  int iw = blockIdx.y * 64 + w * 16;

  floatx4 acc[4], lacc;
#pragma unroll
  for (int ft = 0; ft < 4; ft++)
#pragma unroll
    for (int r = 0; r < 4; r++) acc[ft][r] = 0.f;
#pragma unroll
  for (int r = 0; r < 4; r++) lacc[r] = 0.f;

  float src_r = srcT[bh * 1024 + iw + l15];

  Frag ones;
  ones.u4.x = 0x3F803F80u; ones.u4.y = 0x3F803F80u;
  ones.u4.z = 0x3F803F80u; ones.u4.w = 0x3F803F80u;

  const unsigned short* Wg = WhT + bh * 64 * 1024;
  const float* dbase = &dstT[bh * 1024 + quad * 8];
  int sf0 = t >> 3, skb = t & 7;    // staging: f rows {sf0, sf0+32}, 16B block idx
  int swz = (skb ^ (sf0 & 7)) * 8;  // (sf0+32)&7 == sf0&7

  // prefetch first tile
  uint4 g0 = *(const uint4*)&Wg[sf0 * 1024 + skb * 8];
  uint4 g1 = *(const uint4*)&Wg[(sf0 + 32) * 1024 + skb * 8];

  for (int j0 = 0; j0 < 1024; j0 += 64) {
    __syncthreads();  // prior iter's LDS reads done
    *(uint4*)&Bs[sf0 * 64 + swz] = g0;
    *(uint4*)&Bs[(sf0 + 32) * 64 + swz] = g1;
    if (j0 < 960) {  // prefetch next tile; in flight through the MFMA phase
      g0 = *(const uint4*)&Wg[sf0 * 1024 + j0 + 64 + skb * 8];
      g1 = *(const uint4*)&Wg[(sf0 + 32) * 1024 + j0 + 64 + skb * 8];
    }
    // scores -> A-fragments (VALU, no LDS dependence)
    Frag fragA[2];
#pragma unroll
    for (int jc = 0; jc < 2; jc++) {
      float4 dv0 = *(const float4*)&dbase[j0 + jc * 32];
      float4 dv1 = *(const float4*)&dbase[j0 + jc * 32 + 4];
      float dj[8] = {dv0.x, dv0.y, dv0.z, dv0.w, dv1.x, dv1.y, dv1.z, dv1.w};
      unsigned pw[4];
#pragma unroll
      for (int pr = 0; pr < 4; pr++) {
        float x0 = src_r + dj[pr * 2];
        float x1 = src_r + dj[pr * 2 + 1];
        x0 = fmaxf(x0, 0.2f * x0);  // leaky_relu (alpha<1)
        x1 = fmaxf(x1, 0.2f * x1);
        float p0 = __expf(x0), p1 = __expf(x1);
        pw[pr] = (as_u(p0) >> 16) | (as_u(p1) & 0xffff0000u);  // truncate to bf16x2
      }
      fragA[jc].u4.x = pw[0];
      fragA[jc].u4.y = pw[1];
      fragA[jc].u4.z = pw[2];
      fragA[jc].u4.w = pw[3];
    }
    __syncthreads();  // staging visible
    // MFMA: acc[ft] += P(16x32) x Wh(32x16) ; lacc += P x ones
#pragma unroll
    for (int jc = 0; jc < 2; jc++) {
      Frag fbr[4];
#pragma unroll
      for (int ft = 0; ft < 4; ft++) {
        int f = ft * 16 + l15;
        int kb = jc * 4 + quad;
        fbr[ft] = *(const Frag*)&Bs[f * 64 + (kb ^ (f & 7)) * 8];
      }
#pragma unroll
      for (int ft = 0; ft < 4; ft++)
        acc[ft] = __builtin_amdgcn_mfma_f32_16x16x32_bf16(fragA[jc].s8, fbr[ft].s8,
                                                          acc[ft], 0, 0, 0);
      lacc = __builtin_amdgcn_mfma_f32_16x16x32_bf16(fragA[jc].s8, ones.s8, lacc, 0, 0, 0);
    }
  }
  // epilogue: C row = quad*4+r, col = l15; lacc rows align with acc rows
  float inv[4] = {1.f / lacc[0], 1.f / lacc[1], 1.f / lacc[2], 1.f / lacc[3]};
  int mrow = b * 1024 + iw + quad * 4;
#pragma unroll
  for (int ft = 0; ft < 4; ft++) {
    int col = (bh & 7) * 64 + ft * 16 + l15;
#pragma unroll
    for (int r = 0; r < 4; r++)
      out[(mrow + r) * 512 + col] = acc[ft][r] * inv[r];
  }
}

extern "C" void kernel_launch(void* const* d_in, const int* in_sizes, int n_in,
                              void* d_out, int out_size, void* d_ws, size_t ws_size,
                              hipStream_t stream) {
  const float* X = (const float*)d_in[0];   // (8,1024,768)
  const int* mask = (const int*)d_in[1];    // (8,1024)
  const float* W = (const float*)d_in[2];   // (768,512)
  const float* a = (const float*)d_in[3];   // (128,)
  float* out = (float*)d_out;               // (8,1024,512)

  char* ws = (char*)d_ws;
  unsigned short* WhT = (unsigned short*)ws;                    // 64*64*1024 bf16 = 8388608 B
  unsigned short* WbT = (unsigned short*)(ws + 8388608);        // 512*768 bf16  = 786432 B
  float* srcT = (float*)(ws + 9175040);                         // 64*1024 f32   = 262144 B
  float* dstT = (float*)(ws + 9437184);                         // 64*1024 f32

  conv_w<<<96, 256, 0, stream>>>(W, WbT);
  gemm_xw<<<dim3(128, 8), 256, 0, stream>>>(X, WbT, a, mask, WhT, srcT, dstT);
  gat_attn<<<dim3(64, 16), 256, 0, stream>>>(WhT, srcT, dstT, out);
}